// Round 2
// baseline (8173.701 us; speedup 1.0000x reference)
//
#include <hip/hip_runtime.h>
#include <hip/hip_bf16.h>

// Problem constants
#define B_     32
#define DL_    1024
#define L_     196
#define OUT_   512
#define G4_    2048
#define T_     256      // NS*NW total timesteps
#define VOCAB_ 3266
#define NWG_REC 192
#define NSLOT_  8
#define SLOT_TGT_ (NWG_REC / NSLOT_)   // 24 arrivals per slot

// workspace layout (bytes) — total ~8.9 MB
#define OFF_BAR 0                                   // 257*8 u32 phase counters (16 KB reserved)
#define OFF_X   16384                               // [32][1024] f32
#define OFF_XW1 (OFF_X + B_*DL_*4)                  // [32][2048] f32
#define OFF_B2  (OFF_XW1 + B_*G4_*4)                // [2048] f32
#define OFF_HP  (OFF_B2 + G4_*4)                    // ping-pong h: [2][32][512] bf16
#define OFF_H1  (OFF_HP + 2*B_*OUT_*2)              // [257][32][512] bf16 (all steps, feeds gemm)

__device__ __forceinline__ float sigmf(float v) { return 1.0f / (1.0f + __expf(-v)); }

__device__ __forceinline__ unsigned short f2bf(float f) {
  unsigned u = __float_as_uint(f);
  u = u + 0x7fffu + ((u >> 16) & 1u);   // RNE
  return (unsigned short)(u >> 16);
}

// coherent (agent-scope, bypasses per-XCD L2) 8-byte load of 4 bf16 -> f32x4
__device__ __forceinline__ float4 ld_bf4(const unsigned long long* p) {
  unsigned long long v = __hip_atomic_load(p, __ATOMIC_RELAXED, __HIP_MEMORY_SCOPE_AGENT);
  float4 f;
  f.x = __uint_as_float((unsigned)(v & 0xffffull) << 16);
  f.y = __uint_as_float((unsigned)((v >> 16) & 0xffffull) << 16);
  f.z = __uint_as_float((unsigned)((v >> 32) & 0xffffull) << 16);
  f.w = __uint_as_float((unsigned)((v >> 48) & 0xffffull) << 16);
  return f;
}

// coherent 2-byte store
__device__ __forceinline__ void st_h(unsigned short* p, unsigned short v) {
  __hip_atomic_store(p, v, __ATOMIC_RELAXED, __HIP_MEMORY_SCOPE_AGENT);
}

#define DOT4(A, Hv, Wv) \
  A.x = fmaf(Hv.x, Wv.x, A.x); \
  A.y = fmaf(Hv.y, Wv.y, A.y); \
  A.z = fmaf(Hv.z, Wv.z, A.z); \
  A.w = fmaf(Hv.w, Wv.w, A.w);

// 8-slot tree barrier; watchdog frees the GPU (garbage results, visible fail)
// if co-residency is ever violated — never hang the container.
__device__ __forceinline__ void phase_barrier(unsigned int* bar, int q, int wg, unsigned* dead) {
  __syncthreads();   // drains vmcnt -> all this-WG H stores are globally visible (sc1 write-through)
  const int tid = threadIdx.x;
  if (tid == 0)
    __hip_atomic_fetch_add(&bar[q * NSLOT_ + (wg & (NSLOT_ - 1))], 1u,
                           __ATOMIC_RELEASE, __HIP_MEMORY_SCOPE_AGENT);
  if (tid < NSLOT_ && !*dead) {
    unsigned polls = 0;
    while (__hip_atomic_load(&bar[q * NSLOT_ + tid], __ATOMIC_RELAXED,
                             __HIP_MEMORY_SCOPE_AGENT) < (unsigned)SLOT_TGT_) {
      __builtin_amdgcn_s_sleep(2);
      if (++polls > 10000000u) { *dead = 1; break; }   // ~2 s -> give up, free-run
    }
  }
  __syncthreads();
}

// x[b][d] = sum_i local_features[b][d][i]   (attention collapses to this)
__global__ __launch_bounds__(256) void k_rowsum(const float* __restrict__ lf, float* __restrict__ x) {
  int t = blockIdx.x * 256 + threadIdx.x;         // 32768 threads
  const float4* p = (const float4*)(lf + (size_t)t * L_);   // 196 floats = 784 B, 16B-aligned
  float s = 0.f;
  #pragma unroll
  for (int i = 0; i < 49; ++i) { float4 v = p[i]; s += (v.x + v.y) + (v.z + v.w); }
  x[t] = s;
}

// xw1[b][j] = x[b]·W_ih1[j] + b_ih1[j] + b_hh1[j];  bias2[j] = b_ih2[j]+b_hh2[j]
__global__ __launch_bounds__(256) void k_xw1(const float* __restrict__ x, const float* __restrict__ Wih1,
                                             const float* __restrict__ bih1, const float* __restrict__ bhh1,
                                             const float* __restrict__ bih2, const float* __restrict__ bhh2,
                                             float* __restrict__ xw1, float* __restrict__ bias2) {
  int t = blockIdx.x * 256 + threadIdx.x;         // 65536 threads
  int b = t >> 11, j = t & (G4_ - 1);
  const float4* xp = (const float4*)(x + (size_t)b * DL_);
  const float4* wp = (const float4*)(Wih1 + (size_t)j * DL_);
  float s = 0.f;
  #pragma unroll 8
  for (int i = 0; i < DL_ / 4; ++i) {
    float4 a = xp[i], w = wp[i];
    s += a.x * w.x + a.y * w.y + a.z * w.z + a.w * w.w;
  }
  xw1[t] = s + bih1[j] + bhh1[j];
  if (t < G4_) bias2[t] = bih2[t] + bhh2[t];
}

// Persistent dual-LSTM recurrence (COOPERATIVE launch -> co-residency guaranteed).
// WGs [0,64) = layer1, [64,192) = layer2, software-pipelined one step apart.
// Phase q: layer1 computes step q (reads Hp[q&1], writes Hp[(q+1)&1]);
//          layer2 computes step q-1 (reads Hp[q&1] = h(q), H1[q-1], writes H1[q]).
__global__ __launch_bounds__(256, 1) void k_rec(const float* __restrict__ Whh1,
                                                const float* __restrict__ Wih2,
                                                const float* __restrict__ Whh2,
                                                const float* __restrict__ xw1,
                                                const float* __restrict__ bias2,
                                                unsigned short* __restrict__ Hp,
                                                unsigned short* __restrict__ H1,
                                                unsigned int* __restrict__ bar) {
  __shared__ __align__(16) float lds[16384];   // 64 KB
  float4* lds4 = (float4*)lds;
  const int wg = blockIdx.x, tid = threadIdx.x;
  unsigned dead = 0;

  if (wg < 64) {
    // ---------------- layer 1: 8 u per WG x 32 b, 1 cell/thread ----------------
    const int b = tid & 31, ul = tid >> 5;
    const int u = wg * 8 + ul;
    const float4* w0 = (const float4*)(Whh1 + ((size_t)(0 * OUT_ + u)) * OUT_);
    const float4* w1 = (const float4*)(Whh1 + ((size_t)(1 * OUT_ + u)) * OUT_);
    const float4* w2 = (const float4*)(Whh1 + ((size_t)(2 * OUT_ + u)) * OUT_);
    const float4* w3 = (const float4*)(Whh1 + ((size_t)(3 * OUT_ + u)) * OUT_);
    const float xb0 = xw1[b * G4_ + u];
    const float xb1 = xw1[b * G4_ + OUT_ + u];
    const float xb2 = xw1[b * G4_ + 2 * OUT_ + u];
    const float xb3 = xw1[b * G4_ + 3 * OUT_ + u];
    const float4* lh = lds4 + b * 128;
    float creg = 0.f;

    for (int q = 0; q < T_; ++q) {
      // stage h(q) (32x512 bf16, coherent loads) -> LDS f32, xor-swizzled
      const unsigned long long* src = (const unsigned long long*)(Hp + (size_t)(q & 1) * B_ * OUT_);
      #pragma unroll
      for (int j = 0; j < 16; ++j) {
        int f = j * 256 + tid;
        int row = f >> 7, c = f & 127;
        lds4[row * 128 + (c ^ row)] = ld_bf4(src + f);
      }
      __syncthreads();

      float4 a0 = {0,0,0,0}, a1 = {0,0,0,0}, a2 = {0,0,0,0}, a3 = {0,0,0,0};
      #pragma unroll 4
      for (int c = 0; c < 128; ++c) {
        float4 hv = lh[c ^ b];
        float4 v0 = w0[c]; DOT4(a0, hv, v0);
        float4 v1 = w1[c]; DOT4(a1, hv, v1);
        float4 v2 = w2[c]; DOT4(a2, hv, v2);
        float4 v3 = w3[c]; DOT4(a3, hv, v3);
      }
      float p0 = xb0 + (a0.x + a0.y) + (a0.z + a0.w);
      float p1 = xb1 + (a1.x + a1.y) + (a1.z + a1.w);
      float p2 = xb2 + (a2.x + a2.y) + (a2.z + a2.w);
      float p3 = xb3 + (a3.x + a3.y) + (a3.z + a3.w);
      float ig = sigmf(p0), fg = sigmf(p1), gg = tanhf(p2), og = sigmf(p3);
      creg = fmaf(fg, creg, ig * gg);
      float h = og * tanhf(creg);
      st_h(&Hp[(size_t)((q + 1) & 1) * B_ * OUT_ + b * OUT_ + u], f2bf(h));
      phase_barrier(bar, q, wg, &dead);
      __syncthreads();   // LDS reuse guard
    }
  } else {
    // ---------------- layer 2: 8 u x 16 b per WG, 2-way K-split ----------------
    const int wl = wg - 64;                     // 0..127
    const int bl = tid & 15, kh = (tid >> 4) & 1, ulocal = tid >> 5;
    const int b0 = (wl & 1) * 16;
    const int u = (wl >> 1) * 8 + ulocal;
    const float4* wi0 = (const float4*)(Wih2 + ((size_t)(0 * OUT_ + u)) * OUT_) + kh * 64;
    const float4* wi1 = (const float4*)(Wih2 + ((size_t)(1 * OUT_ + u)) * OUT_) + kh * 64;
    const float4* wi2 = (const float4*)(Wih2 + ((size_t)(2 * OUT_ + u)) * OUT_) + kh * 64;
    const float4* wi3 = (const float4*)(Wih2 + ((size_t)(3 * OUT_ + u)) * OUT_) + kh * 64;
    const float4* wh0 = (const float4*)(Whh2 + ((size_t)(0 * OUT_ + u)) * OUT_) + kh * 64;
    const float4* wh1 = (const float4*)(Whh2 + ((size_t)(1 * OUT_ + u)) * OUT_) + kh * 64;
    const float4* wh2 = (const float4*)(Whh2 + ((size_t)(2 * OUT_ + u)) * OUT_) + kh * 64;
    const float4* wh3 = (const float4*)(Whh2 + ((size_t)(3 * OUT_ + u)) * OUT_) + kh * 64;
    const float bs0 = bias2[u], bs1 = bias2[OUT_ + u], bs2 = bias2[2 * OUT_ + u], bs3 = bias2[3 * OUT_ + u];
    const float4* lh  = lds4 + bl * 128;
    const float4* lh1 = lds4 + 2048 + bl * 128;
    const int kb = kh * 64;
    float c1reg = 0.f;

    phase_barrier(bar, 0, wg, &dead);
    for (int q = 1; q <= T_; ++q) {
      // stage h(q) rows [b0,b0+16) and h1(q-1) rows [b0,b0+16) (coherent loads)
      const unsigned long long* sh  = (const unsigned long long*)(Hp + (size_t)(q & 1) * B_ * OUT_) + b0 * 128;
      const unsigned long long* sh1 = (const unsigned long long*)(H1 + (size_t)(q - 1) * B_ * OUT_) + b0 * 128;
      #pragma unroll
      for (int j = 0; j < 8; ++j) {
        int f = j * 256 + tid;
        int row = f >> 7, c = f & 127;
        int d = row * 128 + (c ^ row);
        lds4[d] = ld_bf4(sh + f);
        lds4[2048 + d] = ld_bf4(sh1 + f);
      }
      __syncthreads();

      float4 a0 = {0,0,0,0}, a1 = {0,0,0,0}, a2 = {0,0,0,0}, a3 = {0,0,0,0};
      #pragma unroll 4
      for (int c4 = 0; c4 < 64; ++c4) {
        int cs = (kb + c4) ^ bl;
        float4 hv = lh[cs];
        float4 g1 = lh1[cs];
        float4 va0 = wi0[c4]; DOT4(a0, hv, va0);
        float4 vb0 = wh0[c4]; DOT4(a0, g1, vb0);
        float4 va1 = wi1[c4]; DOT4(a1, hv, va1);
        float4 vb1 = wh1[c4]; DOT4(a1, g1, vb1);
        float4 va2 = wi2[c4]; DOT4(a2, hv, va2);
        float4 vb2 = wh2[c4]; DOT4(a2, g1, vb2);
        float4 va3 = wi3[c4]; DOT4(a3, hv, va3);
        float4 vb3 = wh3[c4]; DOT4(a3, g1, vb3);
      }
      float s0 = (a0.x + a0.y) + (a0.z + a0.w); s0 += __shfl_xor(s0, 16, 64);
      float s1 = (a1.x + a1.y) + (a1.z + a1.w); s1 += __shfl_xor(s1, 16, 64);
      float s2 = (a2.x + a2.y) + (a2.z + a2.w); s2 += __shfl_xor(s2, 16, 64);
      float s3 = (a3.x + a3.y) + (a3.z + a3.w); s3 += __shfl_xor(s3, 16, 64);
      float p0 = bs0 + s0, p1 = bs1 + s1, p2 = bs2 + s2, p3 = bs3 + s3;
      float ig = sigmf(p0), fg = sigmf(p1), gg = tanhf(p2), og = sigmf(p3);
      c1reg = fmaf(fg, c1reg, ig * gg);
      float h1v = og * tanhf(c1reg);
      if (kh == 0) st_h(&H1[(size_t)q * B_ * OUT_ + (b0 + bl) * OUT_ + u], f2bf(h1v));
      if (q < T_) phase_barrier(bar, q, wg, &dead);
      __syncthreads();   // LDS reuse guard
    }
  }
}

// out[b][n][w][v] = h1(step s=n*32+w)·W_f[v] + b_f[v];  A row m = s*32+b -> H1 flat row m+32
__global__ __launch_bounds__(256, 1) void k_gemm(const unsigned short* __restrict__ H1,
                                                 const float* __restrict__ Wf,
                                                 const float* __restrict__ bfv,
                                                 float* __restrict__ out) {
  __shared__ __align__(16) float As[128 * 36];
  __shared__ __align__(16) float Bs[128 * 36];
  const int mt = blockIdx.x, nt = blockIdx.y, tid = threadIdx.x;
  const int tm = tid >> 4, tv = tid & 15;
  float acc[8][8];
  #pragma unroll
  for (int i = 0; i < 8; ++i)
    #pragma unroll
    for (int j = 0; j < 8; ++j) acc[i][j] = 0.f;

  const unsigned short* Abase = H1 + (size_t)(32 + mt * 128) * OUT_;

  for (int k0 = 0; k0 < OUT_; k0 += 32) {
    #pragma unroll
    for (int j = 0; j < 2; ++j) {
      int a8 = j * 256 + tid;
      int r = a8 >> 2, kp = (a8 & 3) * 8;
      uint4 raw = *(const uint4*)(Abase + (size_t)r * OUT_ + k0 + kp);
      float4 f0, f1;
      f0.x = __uint_as_float(raw.x << 16); f0.y = __uint_as_float(raw.x & 0xffff0000u);
      f0.z = __uint_as_float(raw.y << 16); f0.w = __uint_as_float(raw.y & 0xffff0000u);
      f1.x = __uint_as_float(raw.z << 16); f1.y = __uint_as_float(raw.z & 0xffff0000u);
      f1.z = __uint_as_float(raw.w << 16); f1.w = __uint_as_float(raw.w & 0xffff0000u);
      *(float4*)&As[r * 36 + kp]     = f0;
      *(float4*)&As[r * 36 + kp + 4] = f1;
    }
    #pragma unroll
    for (int j = 0; j < 4; ++j) {
      int b4 = j * 256 + tid;
      int r = b4 >> 3, kp = (b4 & 7) * 4;
      int v = nt * 128 + r;
      float4 fv = {0,0,0,0};
      if (v < VOCAB_) fv = *(const float4*)(Wf + (size_t)v * OUT_ + k0 + kp);
      *(float4*)&Bs[r * 36 + kp] = fv;
    }
    __syncthreads();

    #pragma unroll
    for (int kk = 0; kk < 32; kk += 4) {
      float4 af[8];
      #pragma unroll
      for (int i = 0; i < 8; ++i) af[i] = *(const float4*)&As[(tm + i * 16) * 36 + kk];
      #pragma unroll
      for (int j = 0; j < 8; ++j) {
        float4 bv = *(const float4*)&Bs[(tv + j * 16) * 36 + kk];
        #pragma unroll
        for (int i = 0; i < 8; ++i) {
          acc[i][j] = fmaf(af[i].x, bv.x, acc[i][j]);
          acc[i][j] = fmaf(af[i].y, bv.y, acc[i][j]);
          acc[i][j] = fmaf(af[i].z, bv.z, acc[i][j]);
          acc[i][j] = fmaf(af[i].w, bv.w, acc[i][j]);
        }
      }
    }
    __syncthreads();
  }

  #pragma unroll
  for (int j = 0; j < 8; ++j) {
    int v = nt * 128 + tv + j * 16;
    if (v >= VOCAB_) continue;
    float bias = bfv[v];
    #pragma unroll
    for (int i = 0; i < 8; ++i) {
      int m = mt * 128 + tm + i * 16;
      int bb = m & 31, s = m >> 5;
      out[(size_t)(bb * 256 + s) * VOCAB_ + v] = acc[i][j] + bias;
    }
  }
}

extern "C" void kernel_launch(void* const* d_in, const int* in_sizes, int n_in,
                              void* d_out, int out_size, void* d_ws, size_t ws_size,
                              hipStream_t stream) {
  const float* lf   = (const float*)d_in[0];
  const float* Wih1 = (const float*)d_in[5];
  const float* Whh1 = (const float*)d_in[6];
  const float* bih1 = (const float*)d_in[7];
  const float* bhh1 = (const float*)d_in[8];
  const float* Wih2 = (const float*)d_in[9];
  const float* Whh2 = (const float*)d_in[10];
  const float* bih2 = (const float*)d_in[11];
  const float* bhh2 = (const float*)d_in[12];
  const float* Wf   = (const float*)d_in[13];
  const float* bfv  = (const float*)d_in[14];
  float* out = (float*)d_out;
  char* ws = (char*)d_ws;

  unsigned int*   bar  = (unsigned int*)(ws + OFF_BAR);
  float*          x    = (float*)(ws + OFF_X);
  float*          xw1  = (float*)(ws + OFF_XW1);
  float*          b2   = (float*)(ws + OFF_B2);
  unsigned short* Hp   = (unsigned short*)(ws + OFF_HP);
  unsigned short* H1   = (unsigned short*)(ws + OFF_H1);

  hipMemsetAsync(bar, 0, 16384, stream);
  hipMemsetAsync(Hp,  0, 2 * B_ * OUT_ * 2, stream);   // h(0) = 0 (both ping-pong bufs)
  hipMemsetAsync(H1,  0, B_ * OUT_ * 2, stream);       // h1(0) = 0

  k_rowsum<<<128, 256, 0, stream>>>(lf, x);
  k_xw1<<<256, 256, 0, stream>>>(x, Wih1, bih1, bhh1, bih2, bhh2, xw1, b2);

  void* kargs[] = {(void*)&Whh1, (void*)&Wih2, (void*)&Whh2, (void*)&xw1,
                   (void*)&b2, (void*)&Hp, (void*)&H1, (void*)&bar};
  hipLaunchCooperativeKernel((void*)k_rec, dim3(NWG_REC), dim3(256), kargs, 0, stream);

  k_gemm<<<dim3(64, 26), 256, 0, stream>>>(H1, Wf, bfv, out);
}

// Round 4
// 6975.500 us; speedup vs baseline: 1.1718x; 1.1718x over previous
//
#include <hip/hip_runtime.h>
#include <hip/hip_bf16.h>

// Problem constants
#define B_     32
#define DL_    1024
#define L_     196
#define OUT_   512
#define G4_    2048
#define T_     256      // NS*NW total timesteps
#define VOCAB_ 3266
#define NWG_REC 192
#define NSLOT_  16
#define SLOT_TGT_ (NWG_REC / NSLOT_)   // 12 arrivals per slot
#define SLOT_STRIDE_ 16                // pad each slot to its own 64B line

// workspace layout (bytes)
#define OFF_BAR 0                                   // 256 phases * 16 slots * 64B = 256 KB
#define BAR_BYTES_ (T_ * NSLOT_ * SLOT_STRIDE_ * 4)
#define OFF_X   (OFF_BAR + BAR_BYTES_)              // [32][1024] f32
#define OFF_XW1 (OFF_X + B_*DL_*4)                  // [32][2048] f32
#define OFF_B2  (OFF_XW1 + B_*G4_*4)                // [2048] f32
#define OFF_HP  (OFF_B2 + G4_*4)                    // ping-pong h: [2][32][512] bf16
#define OFF_H1  (OFF_HP + 2*B_*OUT_*2)              // [257][32][512] bf16 (all steps, feeds gemm)

__device__ __forceinline__ float sigmf(float v) { return 1.0f / (1.0f + __expf(-v)); }

__device__ __forceinline__ unsigned short f2bf(float f) {
  unsigned u = __float_as_uint(f);
  u = u + 0x7fffu + ((u >> 16) & 1u);   // RNE
  return (unsigned short)(u >> 16);
}

// coherent (bypass L1+L2, served by L3 = agent coherent point) 8B load of 4 bf16
__device__ __forceinline__ float4 ld_bf4(const unsigned long long* p) {
  unsigned long long v = __hip_atomic_load(p, __ATOMIC_RELAXED, __HIP_MEMORY_SCOPE_AGENT);
  float4 f;
  f.x = __uint_as_float((unsigned)(v & 0xffffull) << 16);
  f.y = __uint_as_float((unsigned)((v >> 16) & 0xffffull) << 16);
  f.z = __uint_as_float((unsigned)((v >> 32) & 0xffffull) << 16);
  f.w = __uint_as_float((unsigned)((v >> 48) & 0xffffull) << 16);
  return f;
}

// coherent coalesced 8B store (write-through past L1/L2, no fence)
__device__ __forceinline__ void st_coh8(unsigned long long* p, unsigned long long v) {
  __hip_atomic_store(p, v, __ATOMIC_RELAXED, __HIP_MEMORY_SCOPE_AGENT);
}

#define DOT4(A, Hv, Wv) \
  A.x = fmaf(Hv.x, Wv.x, A.x); \
  A.y = fmaf(Hv.y, Wv.y, A.y); \
  A.z = fmaf(Hv.z, Wv.z, A.z); \
  A.w = fmaf(Hv.w, Wv.w, A.w);

// Fence-free phase barrier: wave-0 drains its stores (vmcnt), RELAXED add to a
// line-padded slot, RELAXED polls. No release/acquire -> no L2 writeback/invalidate
// (weights stay L2-resident; h traffic is coherent write-through so nothing is dirty).
// Watchdog frees the GPU (visible absmax fail, never a hang) if co-residency breaks.
__device__ __forceinline__ void phase_barrier(unsigned int* bar, int q, int wg, unsigned* dead) {
  const int tid = threadIdx.x;
  if (tid == 0) {
    asm volatile("s_waitcnt vmcnt(0)" ::: "memory");   // this-wave h stores visible (L3)
    __hip_atomic_fetch_add(&bar[(q * NSLOT_ + (wg & (NSLOT_ - 1))) * SLOT_STRIDE_], 1u,
                           __ATOMIC_RELAXED, __HIP_MEMORY_SCOPE_AGENT);
  }
  if (tid < NSLOT_ && !*dead) {
    unsigned polls = 0;
    while (__hip_atomic_load(&bar[(q * NSLOT_ + tid) * SLOT_STRIDE_], __ATOMIC_RELAXED,
                             __HIP_MEMORY_SCOPE_AGENT) < (unsigned)SLOT_TGT_) {
      __builtin_amdgcn_s_sleep(2);
      if (++polls > 10000000u) { *dead = 1; break; }
    }
  }
  __syncthreads();
}

// x[b][d] = sum_i local_features[b][d][i]   (attention collapses to this)
__global__ __launch_bounds__(256) void k_rowsum(const float* __restrict__ lf, float* __restrict__ x) {
  int t = blockIdx.x * 256 + threadIdx.x;         // 32768 threads
  const float4* p = (const float4*)(lf + (size_t)t * L_);
  float s = 0.f;
  #pragma unroll
  for (int i = 0; i < 49; ++i) { float4 v = p[i]; s += (v.x + v.y) + (v.z + v.w); }
  x[t] = s;
}

// xw1[b][j] = x[b]·W_ih1[j] + b_ih1[j] + b_hh1[j];  bias2[j] = b_ih2[j]+b_hh2[j]
__global__ __launch_bounds__(256) void k_xw1(const float* __restrict__ x, const float* __restrict__ Wih1,
                                             const float* __restrict__ bih1, const float* __restrict__ bhh1,
                                             const float* __restrict__ bih2, const float* __restrict__ bhh2,
                                             float* __restrict__ xw1, float* __restrict__ bias2) {
  int t = blockIdx.x * 256 + threadIdx.x;         // 65536 threads
  int b = t >> 11, j = t & (G4_ - 1);
  const float4* xp = (const float4*)(x + (size_t)b * DL_);
  const float4* wp = (const float4*)(Wih1 + (size_t)j * DL_);
  float s = 0.f;
  #pragma unroll 8
  for (int i = 0; i < DL_ / 4; ++i) {
    float4 a = xp[i], w = wp[i];
    s += a.x * w.x + a.y * w.y + a.z * w.z + a.w * w.w;
  }
  xw1[t] = s + bih1[j] + bhh1[j];
  if (t < G4_) bias2[t] = bih2[t] + bhh2[t];
}

// Persistent dual-LSTM recurrence (cooperative launch). WGs [0,64)=layer1, [64,192)=layer2.
// Phase q: layer1 computes step q (reads Hp[q&1], writes Hp[(q+1)&1]);
//          layer2 computes step q-1 (reads Hp[q&1]=h(q), H1[q-1], writes H1[q]).
__global__ __launch_bounds__(256, 1) void k_rec(const float* __restrict__ Whh1,
                                                const float* __restrict__ Wih2,
                                                const float* __restrict__ Whh2,
                                                const float* __restrict__ xw1,
                                                const float* __restrict__ bias2,
                                                unsigned short* __restrict__ Hp,
                                                unsigned short* __restrict__ H1,
                                                unsigned int* __restrict__ bar) {
  __shared__ __align__(16) float lds[16384 + 128];   // 64 KB staging + 512B transpose scratch
  float4* lds4 = (float4*)lds;
  unsigned short* scr = (unsigned short*)(lds + 16384);
  const int wg = blockIdx.x, tid = threadIdx.x;
  unsigned dead = 0;

  if (wg < 64) {
    // ---------------- layer 1: 8 u per WG x 32 b, 1 cell/thread ----------------
    const int b = tid & 31, ul = tid >> 5;
    const int u = wg * 8 + ul;
    const float4* w0 = (const float4*)(Whh1 + ((size_t)(0 * OUT_ + u)) * OUT_);
    const float4* w1 = (const float4*)(Whh1 + ((size_t)(1 * OUT_ + u)) * OUT_);
    const float4* w2 = (const float4*)(Whh1 + ((size_t)(2 * OUT_ + u)) * OUT_);
    const float4* w3 = (const float4*)(Whh1 + ((size_t)(3 * OUT_ + u)) * OUT_);
    const float xb0 = xw1[b * G4_ + u];
    const float xb1 = xw1[b * G4_ + OUT_ + u];
    const float xb2 = xw1[b * G4_ + 2 * OUT_ + u];
    const float xb3 = xw1[b * G4_ + 3 * OUT_ + u];
    const float4* lh = lds4 + b * 128;
    float creg = 0.f;

    for (int q = 0; q < T_; ++q) {
      // stage h(q) (32x512 bf16, coherent loads) -> LDS f32, xor-swizzled
      const unsigned long long* src = (const unsigned long long*)(Hp + (size_t)(q & 1) * B_ * OUT_);
      #pragma unroll
      for (int j = 0; j < 16; ++j) {
        int f = j * 256 + tid;
        int row = f >> 7, c = f & 127;
        lds4[row * 128 + (c ^ row)] = ld_bf4(src + f);
      }
      __syncthreads();

      float4 a0 = {0,0,0,0}, a1 = {0,0,0,0}, a2 = {0,0,0,0}, a3 = {0,0,0,0};
      #pragma unroll 4
      for (int c = 0; c < 128; ++c) {
        float4 hv = lh[c ^ b];
        float4 v0 = w0[c]; DOT4(a0, hv, v0);
        float4 v1 = w1[c]; DOT4(a1, hv, v1);
        float4 v2 = w2[c]; DOT4(a2, hv, v2);
        float4 v3 = w3[c]; DOT4(a3, hv, v3);
      }
      float p0 = xb0 + (a0.x + a0.y) + (a0.z + a0.w);
      float p1 = xb1 + (a1.x + a1.y) + (a1.z + a1.w);
      float p2 = xb2 + (a2.x + a2.y) + (a2.z + a2.w);
      float p3 = xb3 + (a3.x + a3.y) + (a3.z + a3.w);
      float ig = sigmf(p0), fg = sigmf(p1), gg = tanhf(p2), og = sigmf(p3);
      creg = fmaf(fg, creg, ig * gg);
      float h = og * tanhf(creg);

      // LDS transpose -> coalesced 8B coherent stores (layout stays [b][u])
      scr[b * 8 + ul] = f2bf(h);
      __syncthreads();
      if (tid < 64) {
        int row = tid >> 1, part = tid & 1;
        unsigned long long v = *(const unsigned long long*)&scr[row * 8 + part * 4];
        unsigned long long* dst = (unsigned long long*)
            (Hp + (size_t)((q + 1) & 1) * B_ * OUT_ + (size_t)row * OUT_ + wg * 8);
        st_coh8(dst + part, v);
      }
      phase_barrier(bar, q, wg, &dead);
    }
  } else {
    // ---------------- layer 2: 8 u x 16 b per WG, 2-way K-split ----------------
    const int wl = wg - 64;                     // 0..127
    const int bl = tid & 15, kh = (tid >> 4) & 1, ulocal = tid >> 5;
    const int b0 = (wl & 1) * 16;
    const int u = (wl >> 1) * 8 + ulocal;
    const float4* wi0 = (const float4*)(Wih2 + ((size_t)(0 * OUT_ + u)) * OUT_) + kh * 64;
    const float4* wi1 = (const float4*)(Wih2 + ((size_t)(1 * OUT_ + u)) * OUT_) + kh * 64;
    const float4* wi2 = (const float4*)(Wih2 + ((size_t)(2 * OUT_ + u)) * OUT_) + kh * 64;
    const float4* wi3 = (const float4*)(Wih2 + ((size_t)(3 * OUT_ + u)) * OUT_) + kh * 64;
    const float4* wh0 = (const float4*)(Whh2 + ((size_t)(0 * OUT_ + u)) * OUT_) + kh * 64;
    const float4* wh1 = (const float4*)(Whh2 + ((size_t)(1 * OUT_ + u)) * OUT_) + kh * 64;
    const float4* wh2 = (const float4*)(Whh2 + ((size_t)(2 * OUT_ + u)) * OUT_) + kh * 64;
    const float4* wh3 = (const float4*)(Whh2 + ((size_t)(3 * OUT_ + u)) * OUT_) + kh * 64;
    const float bs0 = bias2[u], bs1 = bias2[OUT_ + u], bs2 = bias2[2 * OUT_ + u], bs3 = bias2[3 * OUT_ + u];
    const float4* lh  = lds4 + bl * 128;
    const float4* lh1 = lds4 + 2048 + bl * 128;
    const int kb = kh * 64;
    float c1reg = 0.f;

    phase_barrier(bar, 0, wg, &dead);
    for (int q = 1; q <= T_; ++q) {
      // stage h(q) rows [b0,b0+16) and h1(q-1) rows [b0,b0+16) (coherent loads)
      const unsigned long long* sh  = (const unsigned long long*)(Hp + (size_t)(q & 1) * B_ * OUT_) + b0 * 128;
      const unsigned long long* sh1 = (const unsigned long long*)(H1 + (size_t)(q - 1) * B_ * OUT_) + b0 * 128;
      #pragma unroll
      for (int j = 0; j < 8; ++j) {
        int f = j * 256 + tid;
        int row = f >> 7, c = f & 127;
        int d = row * 128 + (c ^ row);
        lds4[d] = ld_bf4(sh + f);
        lds4[2048 + d] = ld_bf4(sh1 + f);
      }
      __syncthreads();

      float4 a0 = {0,0,0,0}, a1 = {0,0,0,0}, a2 = {0,0,0,0}, a3 = {0,0,0,0};
      #pragma unroll 4
      for (int c4 = 0; c4 < 64; ++c4) {
        int cs = (kb + c4) ^ bl;
        float4 hv = lh[cs];
        float4 g1 = lh1[cs];
        float4 va0 = wi0[c4]; DOT4(a0, hv, va0);
        float4 vb0 = wh0[c4]; DOT4(a0, g1, vb0);
        float4 va1 = wi1[c4]; DOT4(a1, hv, va1);
        float4 vb1 = wh1[c4]; DOT4(a1, g1, vb1);
        float4 va2 = wi2[c4]; DOT4(a2, hv, va2);
        float4 vb2 = wh2[c4]; DOT4(a2, g1, vb2);
        float4 va3 = wi3[c4]; DOT4(a3, hv, va3);
        float4 vb3 = wh3[c4]; DOT4(a3, g1, vb3);
      }
      float s0 = (a0.x + a0.y) + (a0.z + a0.w); s0 += __shfl_xor(s0, 16, 64);
      float s1 = (a1.x + a1.y) + (a1.z + a1.w); s1 += __shfl_xor(s1, 16, 64);
      float s2 = (a2.x + a2.y) + (a2.z + a2.w); s2 += __shfl_xor(s2, 16, 64);
      float s3 = (a3.x + a3.y) + (a3.z + a3.w); s3 += __shfl_xor(s3, 16, 64);
      float p0 = bs0 + s0, p1 = bs1 + s1, p2 = bs2 + s2, p3 = bs3 + s3;
      float ig = sigmf(p0), fg = sigmf(p1), gg = tanhf(p2), og = sigmf(p3);
      c1reg = fmaf(fg, c1reg, ig * gg);
      float h1v = og * tanhf(c1reg);

      // LDS transpose -> coalesced 8B coherent stores (layout stays [b][u])
      if (kh == 0) scr[bl * 8 + ulocal] = f2bf(h1v);
      __syncthreads();
      if (tid < 32) {
        int row = tid >> 1, part = tid & 1;
        unsigned long long v = *(const unsigned long long*)&scr[row * 8 + part * 4];
        unsigned long long* dst = (unsigned long long*)
            (H1 + (size_t)q * B_ * OUT_ + (size_t)(b0 + row) * OUT_ + (wl >> 1) * 8);
        st_coh8(dst + part, v);
      }
      if (q < T_) phase_barrier(bar, q, wg, &dead);
    }
  }
}

// out[b][n][w][v] = h1(step s=n*32+w)·W_f[v] + b_f[v];  A row m = s*32+b -> H1 flat row m+32
__global__ __launch_bounds__(256, 1) void k_gemm(const unsigned short* __restrict__ H1,
                                                 const float* __restrict__ Wf,
                                                 const float* __restrict__ bfv,
                                                 float* __restrict__ out) {
  __shared__ __align__(16) float As[128 * 36];
  __shared__ __align__(16) float Bs[128 * 36];
  const int mt = blockIdx.x, nt = blockIdx.y, tid = threadIdx.x;
  const int tm = tid >> 4, tv = tid & 15;
  float acc[8][8];
  #pragma unroll
  for (int i = 0; i < 8; ++i)
    #pragma unroll
    for (int j = 0; j < 8; ++j) acc[i][j] = 0.f;

  const unsigned short* Abase = H1 + (size_t)(32 + mt * 128) * OUT_;

  for (int k0 = 0; k0 < OUT_; k0 += 32) {
    #pragma unroll
    for (int j = 0; j < 2; ++j) {
      int a8 = j * 256 + tid;
      int r = a8 >> 2, kp = (a8 & 3) * 8;
      uint4 raw = *(const uint4*)(Abase + (size_t)r * OUT_ + k0 + kp);
      float4 f0, f1;
      f0.x = __uint_as_float(raw.x << 16); f0.y = __uint_as_float(raw.x & 0xffff0000u);
      f0.z = __uint_as_float(raw.y << 16); f0.w = __uint_as_float(raw.y & 0xffff0000u);
      f1.x = __uint_as_float(raw.z << 16); f1.y = __uint_as_float(raw.z & 0xffff0000u);
      f1.z = __uint_as_float(raw.w << 16); f1.w = __uint_as_float(raw.w & 0xffff0000u);
      *(float4*)&As[r * 36 + kp]     = f0;
      *(float4*)&As[r * 36 + kp + 4] = f1;
    }
    #pragma unroll
    for (int j = 0; j < 4; ++j) {
      int b4 = j * 256 + tid;
      int r = b4 >> 3, kp = (b4 & 7) * 4;
      int v = nt * 128 + r;
      float4 fv = {0,0,0,0};
      if (v < VOCAB_) fv = *(const float4*)(Wf + (size_t)v * OUT_ + k0 + kp);
      *(float4*)&Bs[r * 36 + kp] = fv;
    }
    __syncthreads();

    #pragma unroll
    for (int kk = 0; kk < 32; kk += 4) {
      float4 af[8];
      #pragma unroll
      for (int i = 0; i < 8; ++i) af[i] = *(const float4*)&As[(tm + i * 16) * 36 + kk];
      #pragma unroll
      for (int j = 0; j < 8; ++j) {
        float4 bv = *(const float4*)&Bs[(tv + j * 16) * 36 + kk];
        #pragma unroll
        for (int i = 0; i < 8; ++i) {
          acc[i][j] = fmaf(af[i].x, bv.x, acc[i][j]);
          acc[i][j] = fmaf(af[i].y, bv.y, acc[i][j]);
          acc[i][j] = fmaf(af[i].z, bv.z, acc[i][j]);
          acc[i][j] = fmaf(af[i].w, bv.w, acc[i][j]);
        }
      }
    }
    __syncthreads();
  }

  #pragma unroll
  for (int j = 0; j < 8; ++j) {
    int v = nt * 128 + tv + j * 16;
    if (v >= VOCAB_) continue;
    float bias = bfv[v];
    #pragma unroll
    for (int i = 0; i < 8; ++i) {
      int m = mt * 128 + tm + i * 16;
      int bb = m & 31, s = m >> 5;
      out[(size_t)(bb * 256 + s) * VOCAB_ + v] = acc[i][j] + bias;
    }
  }
}

extern "C" void kernel_launch(void* const* d_in, const int* in_sizes, int n_in,
                              void* d_out, int out_size, void* d_ws, size_t ws_size,
                              hipStream_t stream) {
  const float* lf   = (const float*)d_in[0];
  const float* Wih1 = (const float*)d_in[5];
  const float* Whh1 = (const float*)d_in[6];
  const float* bih1 = (const float*)d_in[7];
  const float* bhh1 = (const float*)d_in[8];
  const float* Wih2 = (const float*)d_in[9];
  const float* Whh2 = (const float*)d_in[10];
  const float* bih2 = (const float*)d_in[11];
  const float* bhh2 = (const float*)d_in[12];
  const float* Wf   = (const float*)d_in[13];
  const float* bfv  = (const float*)d_in[14];
  float* out = (float*)d_out;
  char* ws = (char*)d_ws;

  unsigned int*   bar  = (unsigned int*)(ws + OFF_BAR);
  float*          x    = (float*)(ws + OFF_X);
  float*          xw1  = (float*)(ws + OFF_XW1);
  float*          b2   = (float*)(ws + OFF_B2);
  unsigned short* Hp   = (unsigned short*)(ws + OFF_HP);
  unsigned short* H1   = (unsigned short*)(ws + OFF_H1);

  (void)hipMemsetAsync(bar, 0, BAR_BYTES_, stream);
  (void)hipMemsetAsync(Hp,  0, 2 * B_ * OUT_ * 2, stream);   // h(0) = 0 (both ping-pong bufs)
  (void)hipMemsetAsync(H1,  0, B_ * OUT_ * 2, stream);       // h1(0) = 0

  k_rowsum<<<128, 256, 0, stream>>>(lf, x);
  k_xw1<<<256, 256, 0, stream>>>(x, Wih1, bih1, bhh1, bih2, bhh2, xw1, b2);

  void* kargs[] = {(void*)&Whh1, (void*)&Wih2, (void*)&Whh2, (void*)&xw1,
                   (void*)&b2, (void*)&Hp, (void*)&H1, (void*)&bar};
  (void)hipLaunchCooperativeKernel((void*)k_rec, dim3(NWG_REC), dim3(256), kargs, 0, stream);

  k_gemm<<<dim3(64, 26), 256, 0, stream>>>(H1, Wf, bfv, out);
}

// Round 7
// 4164.342 us; speedup vs baseline: 1.9628x; 1.6751x over previous
//
#include <hip/hip_runtime.h>
#include <hip/hip_bf16.h>

// Problem constants
#define B_     32
#define DL_    1024
#define L_     196
#define OUT_   512
#define G4_    2048
#define T_     256      // NS*NW total timesteps
#define VOCAB_ 3266
#define NWG_REC 192     // PROVEN cooperative envelope (R4: 192 WGs @ 66048 B LDS)
#define NWG_L1  64
#define NSLOT_  16
#define SLOT_TGT_ (NWG_REC / NSLOT_)   // 12 arrivals per slot
#define SLOT_STRIDE_ 16                // one 64B line per slot

// workspace layout (bytes)
#define OFF_BAR 0
#define BAR_BYTES_ (T_ * NSLOT_ * SLOT_STRIDE_ * 4)
#define OFF_X   (OFF_BAR + BAR_BYTES_)              // [32][1024] f32
#define OFF_XW1 (OFF_X + B_*DL_*4)                  // [32][2048] f32
#define OFF_B2  (OFF_XW1 + B_*G4_*4)                // [2048] f32
#define OFF_HP  (OFF_B2 + G4_*4)                    // ping-pong h: [2][32][512] f16
#define OFF_H1  (OFF_HP + 2*B_*OUT_*2)              // [257][32][512] f16
#define H1_BYTES_ ((size_t)(T_+1)*B_*OUT_*2)

typedef _Float16 h8 __attribute__((ext_vector_type(8)));

// f16-source f32-accumulate dot (v_fma_mix_f32); semantics unambiguous.
__device__ __forceinline__ float dot8(h8 a, h8 b, float s) {
  #pragma unroll
  for (int i = 0; i < 8; ++i) s = fmaf((float)a[i], (float)b[i], s);
  return s;
}

__device__ __forceinline__ float sigmf(float v) { return 1.0f / (1.0f + __expf(-v)); }

__device__ __forceinline__ unsigned short f2h(float f) {
  union { _Float16 h; unsigned short u; } c;
  c.h = (_Float16)f;
  return c.u;
}

// coherent (bypass L1/L2 -> L3 coherent point) 8B load/store — R4-proven
__device__ __forceinline__ unsigned long long ld8(const unsigned long long* p) {
  return __hip_atomic_load(p, __ATOMIC_RELAXED, __HIP_MEMORY_SCOPE_AGENT);
}
__device__ __forceinline__ void st8(unsigned long long* p, unsigned long long v) {
  __hip_atomic_store(p, v, __ATOMIC_RELAXED, __HIP_MEMORY_SCOPE_AGENT);
}

// Fence-free phase barrier; watchdog frees GPU on co-residency loss.
__device__ __forceinline__ void phase_barrier(unsigned int* bar, int q, int wg, unsigned* dead) {
  const int tid = threadIdx.x;
  if (tid == 0) {
    asm volatile("s_waitcnt vmcnt(0)" ::: "memory");
    __hip_atomic_fetch_add(&bar[(q * NSLOT_ + (wg & (NSLOT_ - 1))) * SLOT_STRIDE_], 1u,
                           __ATOMIC_RELAXED, __HIP_MEMORY_SCOPE_AGENT);
  }
  if (tid < NSLOT_ && !*dead) {
    unsigned polls = 0;
    while (__hip_atomic_load(&bar[(q * NSLOT_ + tid) * SLOT_STRIDE_], __ATOMIC_RELAXED,
                             __HIP_MEMORY_SCOPE_AGENT) < (unsigned)SLOT_TGT_) {
      __builtin_amdgcn_s_sleep(2);
      if (++polls > 10000000u) { *dead = 1; break; }
    }
  }
  __syncthreads();
}

// x[b][d] = sum_i local_features[b][d][i]
__global__ __launch_bounds__(256) void k_rowsum(const float* __restrict__ lf, float* __restrict__ x) {
  int t = blockIdx.x * 256 + threadIdx.x;
  const float4* p = (const float4*)(lf + (size_t)t * L_);
  float s = 0.f;
  #pragma unroll
  for (int i = 0; i < 49; ++i) { float4 v = p[i]; s += (v.x + v.y) + (v.z + v.w); }
  x[t] = s;
}

// xw1[b][j] = x[b]·W_ih1[j] + b_ih1[j] + b_hh1[j];  bias2[j] = b_ih2[j]+b_hh2[j]
__global__ __launch_bounds__(256) void k_xw1(const float* __restrict__ x, const float* __restrict__ Wih1,
                                             const float* __restrict__ bih1, const float* __restrict__ bhh1,
                                             const float* __restrict__ bih2, const float* __restrict__ bhh2,
                                             float* __restrict__ xw1, float* __restrict__ bias2) {
  int t = blockIdx.x * 256 + threadIdx.x;
  int b = t >> 11, j = t & (G4_ - 1);
  const float4* xp = (const float4*)(x + (size_t)b * DL_);
  const float4* wp = (const float4*)(Wih1 + (size_t)j * DL_);
  float s = 0.f;
  #pragma unroll 8
  for (int i = 0; i < DL_ / 4; ++i) {
    float4 a = xp[i], w = wp[i];
    s += a.x * w.x + a.y * w.y + a.z * w.z + a.w * w.w;
  }
  xw1[t] = s + bih1[j] + bhh1[j];
  if (t < G4_) bias2[t] = bih2[t] + bhh2[t];
}

// Persistent dual-LSTM recurrence, cooperative, weights cached in LDS as f16.
// WGs [0,64): layer1, 8u x 32b, full k=512 per thread.
// WGs [64,192): layer2, 4u x 16b x 4kq (cat-k 1024), batch in two 16-row half-phases.
__global__ __launch_bounds__(256, 1) void k_rec(const float* __restrict__ Whh1,
                                                const float* __restrict__ Wih2,
                                                const float* __restrict__ Whh2,
                                                const float* __restrict__ xw1,
                                                const float* __restrict__ bias2,
                                                unsigned short* __restrict__ Hp,
                                                unsigned short* __restrict__ H1,
                                                unsigned int* __restrict__ bar) {
  __shared__ __align__(16) unsigned short sm[33024];   // 66048 B — PROVEN size
  unsigned long long* smu = (unsigned long long*)sm;
  const int wg = blockIdx.x, tid = threadIdx.x;
  unsigned dead = 0;
  unsigned long long* Hpu = (unsigned long long*)Hp;
  unsigned long long* H1u = (unsigned long long*)H1;

  if (wg < NWG_L1) {
    // ----------------- layer 1: 8u x 32b, full-k per thread -----------------
    const int b = tid & 31, ul = tid >> 5;       // ul 0..7
    const int u = wg * 8 + ul;
    {   // preload Whh1 rows (8u x 4g) x 512 -> f16 LDS, granule-swizzled
      const int rowid = tid >> 3;                // 0..31
      const int uw = rowid >> 2, g = rowid & 3;
      const int kt = (tid & 7) * 64;
      const float* src = Whh1 + ((size_t)(g * OUT_ + wg * 8 + uw)) * OUT_ + kt;
      #pragma unroll
      for (int e = 0; e < 64; ++e) {
        int k = kt + e, gr = k >> 3, sw = gr ^ ((gr >> 3) & 7);
        sm[16384 + (uw * 4 + g) * 512 + sw * 8 + (k & 7)] = f2h(src[e]);
      }
    }
    const float xb0 = xw1[b * G4_ + 0 * OUT_ + u];
    const float xb1 = xw1[b * G4_ + 1 * OUT_ + u];
    const float xb2 = xw1[b * G4_ + 2 * OUT_ + u];
    const float xb3 = xw1[b * G4_ + 3 * OUT_ + u];
    float creg = 0.f;

    for (int q = 0; q < T_; ++q) {
      // stage h(q): [32][512] f16, granule+row swizzled
      unsigned long long v[16];
      const unsigned long long* src = Hpu + (size_t)(q & 1) * 4096;
      #pragma unroll
      for (int i = 0; i < 16; ++i) v[i] = ld8(src + i * 256 + tid);
      #pragma unroll
      for (int i = 0; i < 16; ++i) {
        int j8 = i * 256 + tid;
        int row = j8 >> 7, col8 = j8 & 127, g8 = col8 >> 1, half = col8 & 1;
        int sw = g8 ^ ((g8 >> 3) & 7) ^ (row & 7);
        smu[row * 128 + sw * 2 + half] = v[i];
      }
      __syncthreads();

      float s0 = 0.f, s1 = 0.f, s2 = 0.f, s3 = 0.f;
      #pragma unroll 4
      for (int g8 = 0; g8 < 64; ++g8) {
        int swc = g8 ^ ((g8 >> 3) & 7);
        h8 hv = *(const h8*)&sm[b * 512 + (swc ^ (b & 7)) * 8];
        const unsigned short* wb = &sm[16384 + (ul * 4) * 512 + swc * 8];
        h8 w0 = *(const h8*)(wb);
        h8 w1 = *(const h8*)(wb + 512);
        h8 w2 = *(const h8*)(wb + 1024);
        h8 w3 = *(const h8*)(wb + 1536);
        s0 = dot8(hv, w0, s0); s1 = dot8(hv, w1, s1);
        s2 = dot8(hv, w2, s2); s3 = dot8(hv, w3, s3);
      }
      float p0 = xb0 + s0, p1 = xb1 + s1, p2 = xb2 + s2, p3 = xb3 + s3;
      float ig = sigmf(p0), fg = sigmf(p1), gg = tanhf(p2), og = sigmf(p3);
      creg = fmaf(fg, creg, ig * gg);
      float h = og * tanhf(creg);
      sm[32768 + b * 8 + ul] = f2h(h);     // scratch region, disjoint from staging
      __syncthreads();
      if (tid < 64) {
        int row = tid >> 1, part = tid & 1;
        st8(Hpu + (size_t)((q + 1) & 1) * 4096 + (size_t)row * 128 + wg * 2 + part,
            smu[8192 + tid]);
      }
      phase_barrier(bar, q, wg, &dead);
    }
  } else {
    // ------- layer 2: 4u x 16b x 4kq, cat-k=[h;h1]=1024, two b-halves -------
    const int wl = wg - NWG_L1;                  // 0..127, u-block
    const int bl = tid & 15, kq = (tid >> 4) & 3, ul = tid >> 6;
    const int u = wl * 4 + ul;
    {   // preload [Wih2 | Whh2] rows (4u x 4g) x 1024 -> f16 LDS
      const int rem = tid & 63, g = rem >> 4, kt = (rem & 15) * 64;
      const int uw = wl * 4 + (tid >> 6);
      #pragma unroll
      for (int e = 0; e < 64; ++e) {
        int kc = kt + e;
        float wv = (kc < 512) ? Wih2[((size_t)(g * OUT_ + uw)) * OUT_ + kc]
                              : Whh2[((size_t)(g * OUT_ + uw)) * OUT_ + (kc - 512)];
        int gr = kc >> 3, sw = gr ^ ((gr >> 3) & 7);
        sm[16384 + ((tid >> 6) * 4 + g) * 1024 + sw * 8 + (kc & 7)] = f2h(wv);
      }
    }
    const float bs0 = bias2[0 * OUT_ + u], bs1 = bias2[1 * OUT_ + u];
    const float bs2 = bias2[2 * OUT_ + u], bs3 = bias2[3 * OUT_ + u];
    float c1a = 0.f, c1b = 0.f;                  // cell state for b=bl and b=16+bl

    phase_barrier(bar, 0, wg, &dead);
    for (int q = 1; q <= T_; ++q) {
      const unsigned long long* sh  = Hpu + (size_t)(q & 1) * 4096;
      const unsigned long long* sh1 = H1u + (size_t)(q - 1) * 4096;
      #pragma unroll
      for (int hp = 0; hp < 2; ++hp) {
        const int b0 = hp * 16;
        // stage x_cat rows [b0,b0+16): cols 0-511 <- h(q), 512-1023 <- h1(q-1)
        unsigned long long v[16];
        #pragma unroll
        for (int i = 0; i < 16; ++i) {
          int j8 = i * 256 + tid;
          int part = j8 >> 11, jj = j8 & 2047;
          int row = jj >> 7, col8 = jj & 127;
          v[i] = ld8((part ? sh1 : sh) + (size_t)(b0 + row) * 128 + col8);
        }
        #pragma unroll
        for (int i = 0; i < 16; ++i) {
          int j8 = i * 256 + tid;
          int part = j8 >> 11, jj = j8 & 2047;
          int row = jj >> 7, col8 = jj & 127;
          int catg = part * 64 + (col8 >> 1), half = col8 & 1;
          int sw = catg ^ ((catg >> 3) & 7) ^ (row & 7);
          smu[row * 256 + sw * 2 + half] = v[i];
        }
        __syncthreads();

        float s0 = 0.f, s1 = 0.f, s2 = 0.f, s3 = 0.f;
        #pragma unroll 4
        for (int i = 0; i < 32; ++i) {
          int cg = kq * 32 + i;
          int swc = cg ^ ((cg >> 3) & 7);
          h8 xv = *(const h8*)&sm[bl * 1024 + (swc ^ (bl & 7)) * 8];
          const unsigned short* wb = &sm[16384 + (ul * 4) * 1024 + swc * 8];
          h8 w0 = *(const h8*)(wb);
          h8 w1 = *(const h8*)(wb + 1024);
          h8 w2 = *(const h8*)(wb + 2048);
          h8 w3 = *(const h8*)(wb + 3072);
          s0 = dot8(xv, w0, s0); s1 = dot8(xv, w1, s1);
          s2 = dot8(xv, w2, s2); s3 = dot8(xv, w3, s3);
        }
        s0 += __shfl_xor(s0, 16, 64); s0 += __shfl_xor(s0, 32, 64);
        s1 += __shfl_xor(s1, 16, 64); s1 += __shfl_xor(s1, 32, 64);
        s2 += __shfl_xor(s2, 16, 64); s2 += __shfl_xor(s2, 32, 64);
        s3 += __shfl_xor(s3, 16, 64); s3 += __shfl_xor(s3, 32, 64);
        float p0 = bs0 + s0, p1 = bs1 + s1, p2 = bs2 + s2, p3 = bs3 + s3;
        float ig = sigmf(p0), fg = sigmf(p1), gg = tanhf(p2), og = sigmf(p3);
        float c1 = (hp == 0) ? c1a : c1b;
        c1 = fmaf(fg, c1, ig * gg);
        if (hp == 0) c1a = c1; else c1b = c1;
        float h1v = og * tanhf(c1);
        if (kq == 0) sm[32768 + bl * 4 + ul] = f2h(h1v);
        __syncthreads();
        if (tid < 16) st8(H1u + (size_t)q * 4096 + (size_t)(b0 + tid) * 128 + wl,
                          smu[8192 + tid]);
        __syncthreads();   // scratch/staging reuse guard between halves
      }
      if (q < T_) phase_barrier(bar, q, wg, &dead);
    }
  }
}

// out[b][n][w][v] = h1(step s=n*32+w)·W_f[v] + b_f[v];  A row m = s*32+b -> H1 flat row m+32
__global__ __launch_bounds__(256, 1) void k_gemm(const unsigned short* __restrict__ H1,
                                                 const float* __restrict__ Wf,
                                                 const float* __restrict__ bfv,
                                                 float* __restrict__ out) {
  __shared__ __align__(16) float As[128 * 36];
  __shared__ __align__(16) float Bs[128 * 36];
  const int mt = blockIdx.x, nt = blockIdx.y, tid = threadIdx.x;
  const int tm = tid >> 4, tv = tid & 15;
  float acc[8][8];
  #pragma unroll
  for (int i = 0; i < 8; ++i)
    #pragma unroll
    for (int j = 0; j < 8; ++j) acc[i][j] = 0.f;

  const unsigned short* Abase = H1 + (size_t)(32 + mt * 128) * OUT_;

  for (int k0 = 0; k0 < OUT_; k0 += 32) {
    #pragma unroll
    for (int j = 0; j < 2; ++j) {
      int a8 = j * 256 + tid;
      int r = a8 >> 2, kp = (a8 & 3) * 8;
      h8 hv = *(const h8*)(Abase + (size_t)r * OUT_ + k0 + kp);
      float4 f0 = { (float)hv[0], (float)hv[1], (float)hv[2], (float)hv[3] };
      float4 f1 = { (float)hv[4], (float)hv[5], (float)hv[6], (float)hv[7] };
      *(float4*)&As[r * 36 + kp]     = f0;
      *(float4*)&As[r * 36 + kp + 4] = f1;
    }
    #pragma unroll
    for (int j = 0; j < 4; ++j) {
      int b4 = j * 256 + tid;
      int r = b4 >> 3, kp = (b4 & 7) * 4;
      int vv = nt * 128 + r;
      float4 fv = {0, 0, 0, 0};
      if (vv < VOCAB_) fv = *(const float4*)(Wf + (size_t)vv * OUT_ + k0 + kp);
      *(float4*)&Bs[r * 36 + kp] = fv;
    }
    __syncthreads();

    #pragma unroll
    for (int kk = 0; kk < 32; kk += 4) {
      float4 af[8];
      #pragma unroll
      for (int i = 0; i < 8; ++i) af[i] = *(const float4*)&As[(tm + i * 16) * 36 + kk];
      #pragma unroll
      for (int j = 0; j < 8; ++j) {
        float4 bv = *(const float4*)&Bs[(tv + j * 16) * 36 + kk];
        #pragma unroll
        for (int i = 0; i < 8; ++i) {
          acc[i][j] = fmaf(af[i].x, bv.x, acc[i][j]);
          acc[i][j] = fmaf(af[i].y, bv.y, acc[i][j]);
          acc[i][j] = fmaf(af[i].z, bv.z, acc[i][j]);
          acc[i][j] = fmaf(af[i].w, bv.w, acc[i][j]);
        }
      }
    }
    __syncthreads();
  }

  #pragma unroll
  for (int j = 0; j < 8; ++j) {
    int vv = nt * 128 + tv + j * 16;
    if (vv >= VOCAB_) continue;
    float bias = bfv[vv];
    #pragma unroll
    for (int i = 0; i < 8; ++i) {
      int m = mt * 128 + tm + i * 16;
      int bb = m & 31, s = m >> 5;
      out[(size_t)(bb * 256 + s) * VOCAB_ + vv] = acc[i][j] + bias;
    }
  }
}

extern "C" void kernel_launch(void* const* d_in, const int* in_sizes, int n_in,
                              void* d_out, int out_size, void* d_ws, size_t ws_size,
                              hipStream_t stream) {
  const float* lf   = (const float*)d_in[0];
  const float* Wih1 = (const float*)d_in[5];
  const float* Whh1 = (const float*)d_in[6];
  const float* bih1 = (const float*)d_in[7];
  const float* bhh1 = (const float*)d_in[8];
  const float* Wih2 = (const float*)d_in[9];
  const float* Whh2 = (const float*)d_in[10];
  const float* bih2 = (const float*)d_in[11];
  const float* bhh2 = (const float*)d_in[12];
  const float* Wf   = (const float*)d_in[13];
  const float* bfv  = (const float*)d_in[14];
  float* out = (float*)d_out;
  char* ws = (char*)d_ws;

  unsigned int*   bar  = (unsigned int*)(ws + OFF_BAR);
  float*          x    = (float*)(ws + OFF_X);
  float*          xw1  = (float*)(ws + OFF_XW1);
  float*          b2   = (float*)(ws + OFF_B2);
  unsigned short* Hp   = (unsigned short*)(ws + OFF_HP);
  unsigned short* H1   = (unsigned short*)(ws + OFF_H1);

  (void)hipMemsetAsync(bar, 0, BAR_BYTES_, stream);
  (void)hipMemsetAsync(Hp,  0, 2 * B_ * OUT_ * 2, stream);   // h(0)=0, both frames
  (void)hipMemsetAsync(H1,  0, H1_BYTES_, stream);           // ALL frames: distinct fail signature

  k_rowsum<<<128, 256, 0, stream>>>(lf, x);
  k_xw1<<<256, 256, 0, stream>>>(x, Wih1, bih1, bhh1, bih2, bhh2, xw1, b2);

  void* kargs[] = {(void*)&Whh1, (void*)&Wih2, (void*)&Whh2, (void*)&xw1,
                   (void*)&b2, (void*)&Hp, (void*)&H1, (void*)&bar};
  hipError_t cerr = hipLaunchCooperativeKernel((void*)k_rec, dim3(NWG_REC), dim3(256),
                                               kargs, 0, stream);
  if (cerr != hipSuccess) {
    // fallback: plain launch (192 WGs co-reside at 1 WG/CU; watchdog guards hang)
    k_rec<<<NWG_REC, 256, 0, stream>>>(Whh1, Wih2, Whh2, xw1, b2, Hp, H1, bar);
  }

  k_gemm<<<dim3(64, 26), 256, 0, stream>>>(H1, Wf, bfv, out);
}